// Round 1
// baseline (215.713 us; speedup 1.0000x reference)
//
#include <hip/hip_runtime.h>
#include <math.h>

#define TT 16384            // tokens
#define HD 4096             // hidden
#define NE 64               // experts
#define TM 32               // tokens per block
#define BK 64               // h-chunk per iteration
#define NKT (HD / BK)       // 64 k-iterations
#define NBLK (TT / TM)      // 512 blocks

// ---- async global->LDS, 16B per lane (dest = wave-uniform base + lane*16) ----
__device__ __forceinline__ void async_copy16(const float* src, float* dst) {
  __builtin_amdgcn_global_load_lds(
      (const __attribute__((address_space(1))) void*)src,
      (__attribute__((address_space(3))) void*)dst, 16, 0, 0);
}

#define FMA4(A, HV, WV)                                       \
  A = fmaf((HV).x, (WV).x, A); A = fmaf((HV).y, (WV).y, A);   \
  A = fmaf((HV).z, (WV).z, A); A = fmaf((HV).w, (WV).w, A);

// swizzle: physical byte x within a 256B row holds logical h = ((x ^ swz(row))>>2)
// swzH(row)=((row>>1)&7)<<4 for the token tile, swzW(row)=((row>>2)&7)<<4 for W.

__launch_bounds__(256, 2)
__global__ void router_main(const float* __restrict__ X,
                            const float* __restrict__ W,
                            float* __restrict__ out,
                            float* __restrict__ pP,
                            float* __restrict__ pC,
                            float* __restrict__ pZ) {
  __shared__ __align__(16) float sH[2][TM * BK];   // 2 x 8 KB
  __shared__ __align__(16) float sW[2][NE * BK];   // 2 x 16 KB
  __shared__ float psW[4][NE];
  __shared__ float cf[NE];
  __shared__ float zb[4];

  const int tid  = threadIdx.x;
  const int blk  = blockIdx.x;
  const int tx   = tid & 15;   // expert group (4 experts each)
  const int ty   = tid >> 4;   // token group (2 tokens each), 0..15
  const int wv   = tid >> 6;   // wave id 0..3
  const int lane = tid & 63;

  if (tid < NE) cf[tid] = 0.0f;

  // ---- staging source pointers (pre-swizzled global columns) ----
  const int xoff = (tid & 15) << 4;   // byte offset within a 256B row
  const float* srcH[2];
  const float* srcW[4];
#pragma unroll
  for (int p = 0; p < 2; ++p) {
    const int r = ty + p * 16;                       // token row 0..31
    const int sw = ((r >> 1) & 7) << 4;
    srcH[p] = X + (size_t)(blk * TM + r) * HD + ((xoff ^ sw) >> 2);
  }
#pragma unroll
  for (int p = 0; p < 4; ++p) {
    const int e = ty + p * 16;                       // expert row 0..63
    const int sw = ((e >> 2) & 7) << 4;
    srcW[p] = W + (size_t)e * HD + ((xoff ^ sw) >> 2);
  }

  auto stage = [&](int b, int kt) {
    const int o = kt * BK;
    float* dH = &sH[b][wv * 256];
    async_copy16(srcH[0] + o, dH);
    async_copy16(srcH[1] + o, dH + 1024);
    float* dW = &sW[b][wv * 256];
    async_copy16(srcW[0] + o, dW);
    async_copy16(srcW[1] + o, dW + 1024);
    async_copy16(srcW[2] + o, dW + 2048);
    async_copy16(srcW[3] + o, dW + 3072);
  };

  float acc[2][4] = {{0.f, 0.f, 0.f, 0.f}, {0.f, 0.f, 0.f, 0.f}};
  const int Hswz = (ty & 7) << 4;   // == swzH(2*ty+i), i<2
  const int Wswz = (tx & 7) << 4;   // == swzW(4*tx+j), j<4

  auto compute = [&](int b) {
    const char* hb = (const char*)(&sH[b][0]) + (ty << 9);    // token byte base
    const char* wb = (const char*)(&sW[b][0]) + (tx << 10);   // expert byte base
#pragma unroll
    for (int h4 = 0; h4 < 16; ++h4) {
      const int oH = (h4 << 4) ^ Hswz;
      const int oW = (h4 << 4) ^ Wswz;
      const float4 h0 = *(const float4*)(hb + oH);
      const float4 h1 = *(const float4*)(hb + oH + 256);
      const float4 w0 = *(const float4*)(wb + oW);
      const float4 w1 = *(const float4*)(wb + oW + 256);
      const float4 w2 = *(const float4*)(wb + oW + 512);
      const float4 w3 = *(const float4*)(wb + oW + 768);
      FMA4(acc[0][0], h0, w0) FMA4(acc[0][1], h0, w1)
      FMA4(acc[0][2], h0, w2) FMA4(acc[0][3], h0, w3)
      FMA4(acc[1][0], h1, w0) FMA4(acc[1][1], h1, w1)
      FMA4(acc[1][2], h1, w2) FMA4(acc[1][3], h1, w3)
    }
  };

  // ---- 2-phase pipelined K loop ----
  int buf = 0;
  stage(0, 0);
  __syncthreads();
  for (int kt = 0; kt < NKT; ++kt) {
    if (kt + 1 < NKT) stage(buf ^ 1, kt + 1);   // issue next tile (async)
    compute(buf);                               // consume current tile
    __syncthreads();                            // drains vmcnt + barrier
    buf ^= 1;
  }

  // ---- fused epilogue: softmax / top-2 / losses ----
  float psum[4] = {0.f, 0.f, 0.f, 0.f};
  float zc = 0.0f;
#pragma unroll
  for (int i = 0; i < 2; ++i) {
    const float l0 = acc[i][0], l1 = acc[i][1], l2 = acc[i][2], l3 = acc[i][3];
    float m = fmaxf(fmaxf(l0, l1), fmaxf(l2, l3));
    m = fmaxf(m, __shfl_xor(m, 1));
    m = fmaxf(m, __shfl_xor(m, 2));
    m = fmaxf(m, __shfl_xor(m, 4));
    m = fmaxf(m, __shfl_xor(m, 8));
    const float e0 = expf(l0 - m), e1 = expf(l1 - m);
    const float e2 = expf(l2 - m), e3 = expf(l3 - m);
    float zs = (e0 + e1) + (e2 + e3);
    zs += __shfl_xor(zs, 1);
    zs += __shfl_xor(zs, 2);
    zs += __shfl_xor(zs, 4);
    zs += __shfl_xor(zs, 8);
    const float p0 = e0 / zs, p1 = e1 / zs, p2 = e2 / zs, p3 = e3 / zs;
    psum[0] += p0; psum[1] += p1; psum[2] += p2; psum[3] += p3;

    // local top-2 among this thread's 4 experts (ascending index => ties keep lower)
    float v1 = p0, v2 = p1; int i1 = 4 * tx, i2 = 4 * tx + 1;
    if (p1 > p0) { v1 = p1; i1 = 4 * tx + 1; v2 = p0; i2 = 4 * tx; }
    if (p2 > v1) { v2 = v1; i2 = i1; v1 = p2; i1 = 4 * tx + 2; }
    else if (p2 > v2) { v2 = p2; i2 = 4 * tx + 2; }
    if (p3 > v1) { v2 = v1; i2 = i1; v1 = p3; i1 = 4 * tx + 3; }
    else if (p3 > v2) { v2 = p3; i2 = 4 * tx + 3; }

    // butterfly merge across the 16 lanes holding this token
#pragma unroll
    for (int s = 1; s <= 8; s <<= 1) {
      const float ov1 = __shfl_xor(v1, s); const int oi1 = __shfl_xor(i1, s);
      const float ov2 = __shfl_xor(v2, s); const int oi2 = __shfl_xor(i2, s);
      const bool o1 = (ov1 > v1) || (ov1 == v1 && oi1 < i1);
      if (o1) {
        const bool o2 = (ov2 > v1) || (ov2 == v1 && oi2 < i1);
        v2 = o2 ? ov2 : v1; i2 = o2 ? oi2 : i1;
        v1 = ov1; i1 = oi1;
      } else {
        const bool o2 = (ov1 > v2) || (ov1 == v2 && oi1 < i2);
        v2 = o2 ? ov1 : v2; i2 = o2 ? oi1 : i2;
      }
    }

    const float lz = m + logf(zs);
    if (tx == 0) {
      const int t = blk * TM + 2 * ty + i;
      const float den = v1 + v2 + 1e-9f;
      out[2 * t]     = v1 / den;
      out[2 * t + 1] = v2 / den;
      out[2 * TT + 2 * t]     = (float)i1;
      out[2 * TT + 2 * t + 1] = (float)i2;
      atomicAdd(&cf[i1], 1.0f);
      atomicAdd(&cf[i2], 1.0f);
      zc += lz * lz;
    }
  }

  // reduce prob-sums across the 4 token-groups of this wave (same tx)
#pragma unroll
  for (int j = 0; j < 4; ++j) {
    psum[j] += __shfl_xor(psum[j], 16);
    psum[j] += __shfl_xor(psum[j], 32);
  }
  if (lane < 16) {
#pragma unroll
    for (int j = 0; j < 4; ++j) psW[wv][4 * lane + j] = psum[j];
  }
  float z = zc;   // nonzero only on tx==0 lanes
#pragma unroll
  for (int s = 1; s <= 32; s <<= 1) z += __shfl_xor(z, s);
  if (lane == 0) zb[wv] = z;
  __syncthreads();

  if (tid < NE) {
    pP[blk * NE + tid] = psW[0][tid] + psW[1][tid] + psW[2][tid] + psW[3][tid];
    pC[blk * NE + tid] = cf[tid];
  }
  if (tid == 0) pZ[blk] = zb[0] + zb[1] + zb[2] + zb[3];
}

__global__ void router_final(const float* __restrict__ pP,
                             const float* __restrict__ pC,
                             const float* __restrict__ pZ,
                             float* __restrict__ out) {
  const int e = threadIdx.x;  // 64 threads = 1 wave
  float sP = 0.f, sC = 0.f;
  for (int b = 0; b < NBLK; ++b) {
    sP += pP[b * NE + e];
    sC += pC[b * NE + e];
  }
  const float f = sC * (1.0f / (TT * 2.0f));      // tokens_per_expert/(T*K)
  const float P = sP * (1.0f / (float)TT);        // mean prob
  out[4 * TT + 2 + e] = f;                        // expert_util
  float term = f * P;
#pragma unroll
  for (int s = 1; s <= 32; s <<= 1) term += __shfl_xor(term, s);
  float zs = 0.f;
  for (int b = e; b < NBLK; b += NE) zs += pZ[b];
#pragma unroll
  for (int s = 1; s <= 32; s <<= 1) zs += __shfl_xor(zs, s);
  if (e == 0) {
    out[4 * TT]     = 0.01f * ((float)NE * term);      // aux loss
    out[4 * TT + 1] = 0.001f * (zs / (float)TT);       // z loss
  }
}

extern "C" void kernel_launch(void* const* d_in, const int* in_sizes, int n_in,
                              void* d_out, int out_size, void* d_ws, size_t ws_size,
                              hipStream_t stream) {
  const float* X = (const float*)d_in[0];   // [16384, 4096] f32
  const float* W = (const float*)d_in[1];   // [64, 4096] f32
  float* out = (float*)d_out;
  float* pP = (float*)d_ws;                 // [512][64]
  float* pC = pP + NBLK * NE;               // [512][64]
  float* pZ = pC + NBLK * NE;               // [512]
  (void)in_sizes; (void)n_in; (void)out_size; (void)ws_size;

  router_main<<<dim3(NBLK), dim3(256), 0, stream>>>(X, W, out, pP, pC, pZ);
  router_final<<<dim3(1), dim3(NE), 0, stream>>>(pP, pC, pZ, out);
}